// Round 8
// baseline (199.684 us; speedup 1.0000x reference)
//
#include <hip/hip_runtime.h>

#define C_CH 173
#define L_IN 400
#define EPSV 1e-5f
#define KFEAT 55360  // C*32*10

typedef __fp16   fp16x2 __attribute__((ext_vector_type(2)));
typedef _Float16 f16x8  __attribute__((ext_vector_type(8)));
typedef float    f32x4  __attribute__((ext_vector_type(4)));
typedef float    f32x16 __attribute__((ext_vector_type(16)));

// y1T row: 16 f16 + 1 pad dword = 9 dwords (R2/R3-proven, conflict-free).
#define Y1T_STRIDE_I 9
#define Y1T_ROWS   406  // row r = y1 time t+3; rows 0..2, 403..405 zeroed halo

// segmax: [f][sub], sub = 0..99. Stride 102 f16 = 51 dwords (R3-proven).
#define SEG_STRIDE 102

#define N1 (173 * 3584)  // w2T elems
#define N2 (173 * 512)   // w1T elems
#define N3 (173 * 96)    // BN consts per c
#define NH 8192          // h accumulator (zeroed in prep; fc1 atomicAdds)
#define NA4 885760       // afrag int4 count (= 128*55360 f16 / 8)
#define PREP_BASE (N1 + N2 + N3 + NH)

// featF: fc1 B-fragment layout [c][kh][s][g][lane][8r] f16.
//   k_local = f*10+p in [0,320): kh=k>=160, s=(k-160kh)>>4, ko=k&15,
//   half=ko>>3, r=ko&7; g=b>>5, lane=half*32+(b&31).
// afrag: fc1 A-fragment layout [c][kh][s][jq][lane][8r] f16 of wc1:
//   j = jq*32+(lane&31), k = c*320+kh*160+s*16+(lane>>5)*8+r.
// Both give perfectly coalesced b128 wave loads in fc1 (R7 post-mortem:
// fc1's 32-rows-per-wave gather had 4x line overfetch = ~90us tail hog).

// ---------------------------------------------------------------------------
// Prep kernel: per-channel weight layouts + BN consts + zero h + (optional)
// wc1 -> afrag f16 fragment pack.
// ---------------------------------------------------------------------------
__global__ __launch_bounds__(256) void prep_kernel(
    const float* __restrict__ w1, const float* __restrict__ b1,
    const float* __restrict__ g1, const float* __restrict__ beta1,
    const float* __restrict__ m1, const float* __restrict__ v1,
    const float* __restrict__ w2, const float* __restrict__ b2,
    const float* __restrict__ g2, const float* __restrict__ beta2,
    const float* __restrict__ m2, const float* __restrict__ v2,
    const float* __restrict__ wc1,
    _Float16* __restrict__ w2T_g, _Float16* __restrict__ w1T_g,
    float* __restrict__ sc_g, float* __restrict__ h_ws,
    _Float16* __restrict__ afrag_g, int doA)
{
    const int idx = blockIdx.x * 256 + threadIdx.x;
    if (idx < N1) {
        int c = idx / 3584, r = idx - c * 3584;
        int dt = r >> 9, fg = r & 511;
        int f = fg >> 4, g = fg & 15;
        w2T_g[idx] = (_Float16)w2[c * 3584 + f * 112 + g * 7 + dt];
    } else if (idx < N1 + N2) {
        int j = idx - N1;
        int c = j / 512, r = j - c * 512;
        int g = r >> 5, k = r & 31;
        w1T_g[j] = (k < 9) ? (_Float16)w1[c * 144 + g * 9 + k] : (_Float16)0.0f;
    } else if (idx < N1 + N2 + N3) {
        int j = idx - N1 - N2;
        int c = j / 96, r = j - c * 96;
        float o;
        if (r < 32) {
            int g  = r & 15;
            int cf = c * 16 + g;
            float inv = g1[cf] * rsqrtf(v1[cf] + EPSV);
            o = (r < 16) ? inv : (b1[cf] - m1[cf]) * inv + beta1[cf];
        } else {
            int f  = (r - 32) & 31;
            int cf = c * 32 + f;
            float inv = g2[cf] * rsqrtf(v2[cf] + EPSV);
            o = (r < 64) ? inv : (b2[cf] - m2[cf]) * inv + beta2[cf];
        }
        sc_g[j] = o;
    } else if (idx < PREP_BASE) {
        h_ws[idx - N1 - N2 - N3] = 0.0f;
    } else if (doA) {
        const int i = idx - PREP_BASE;
        if (i >= NA4) return;
        const int lane = i & 63;
        int t = i >> 6;
        const int jq = t & 3; t >>= 2;
        const int s  = t % 10; t /= 10;
        const int kh = t & 1;
        const int c  = t >> 1;
        const int j  = jq * 32 + (lane & 31);
        const int kg = c * 320 + kh * 160 + s * 16 + (lane >> 5) * 8;
        // lanes l and l+32 together consume exactly one 64B line of row j.
        const float* wp = wc1 + (size_t)j * KFEAT + kg;
        const float4 a0 = *(const float4*)wp;
        const float4 a1 = *(const float4*)(wp + 4);
        union { fp16x2 v2[4]; int4 q; } a;
        a.v2[0] = __builtin_amdgcn_cvt_pkrtz(a0.x, a0.y);
        a.v2[1] = __builtin_amdgcn_cvt_pkrtz(a0.z, a0.w);
        a.v2[2] = __builtin_amdgcn_cvt_pkrtz(a1.x, a1.y);
        a.v2[3] = __builtin_amdgcn_cvt_pkrtz(a1.z, a1.w);
        ((int4*)afrag_g)[i] = a.q;
    }
}

// ---------------------------------------------------------------------------
// Tower kernel: EXACT R3/R7 configuration (70.8-73.1us, best known) except
// the pool-stage output goes to featF (fc1 B-fragment layout) — the write
// was already a 2B scatter, so the layout change is free here and makes
// fc1's B-loads coalesced.
// ---------------------------------------------------------------------------
__global__ __launch_bounds__(320, 7) void tower_kernel(
    const float* __restrict__ x,
    const _Float16* __restrict__ w2T_g, const _Float16* __restrict__ w1T_g,
    const float* __restrict__ sc_g,
    _Float16* __restrict__ featF)
{
    __shared__ __align__(16) _Float16 xa_s[432];             // xa[i] = x_s[i]
    __shared__ __align__(16) _Float16 xb_s[432];             // xb[i] = x_s[i+1]
    __shared__ __align__(16) _Float16 w1T_s[16 * 32];        // [g][k]
    __shared__ __align__(16) _Float16 y1T_s[Y1T_ROWS * 2 * Y1T_STRIDE_I];
    __shared__ __align__(16) _Float16 w2T_s[7 * 512];        // [dt][f][g]
    __shared__ _Float16               segmax_s[32 * SEG_STRIDE]; // [f][sub]
    __shared__ __align__(16) float    cst_s[96];  // s1[16] sh1[16] s2[32] sh2[32]

    const int c   = blockIdx.x;
    const int tid = threadIdx.x;

    // ---- once-per-block staging (coalesced, no div/cvt/scatter) ----
    {
        const int4* w2src = (const int4*)(w2T_g + (size_t)c * 3584);
        for (int i = tid; i < 448; i += 320) ((int4*)w2T_s)[i] = w2src[i];
        const int4* w1src = (const int4*)(w1T_g + c * 512);
        if (tid < 64) ((int4*)w1T_s)[tid] = w1src[tid];
        const float4* csrc = (const float4*)(sc_g + c * 96);
        if (tid >= 64 && tid < 88) ((float4*)cst_s)[tid - 64] = csrc[tid - 64];
        // zero y1T halo rows 0..2 and 403..405 (6 rows x 9 dwords)
        if (tid >= 88 && tid < 142) {
            int i = tid - 88;
            int r = i / 9, cx = i - r * 9;
            int row = (r < 3) ? r : (400 + r);
            ((int*)y1T_s)[row * Y1T_STRIDE_I + cx] = 0;
        }
    }
    __syncthreads();
    // per-lane BN consts for conv2/pool (f = tid&31 in both scopes)
    const float s2f  = cst_s[32 + (tid & 31)];
    const float sh2f = cst_s[64 + (tid & 31)];

    // ---- hoisted conv2 weight fragments (loop-invariant across batches) ----
    const int nlaneH = tid & 31;
    const int halfH  = (tid >> 5) & 1;
    union F8q { int4 q; f16x8 h; } af[7];
#pragma unroll
    for (int dt = 0; dt < 7; ++dt)
        af[dt].q = *(const int4*)((const int*)w2T_s + dt * 256 + nlaneH * 8 + halfH * 4);

    for (int nb = 0; nb < 4; ++nb) {
        const int b = blockIdx.y * 4 + nb;

        // ---- stage x as f16 parity copies ----
        const float* xrow = x + ((size_t)b * C_CH + c) * L_IN;
        for (int i = tid; i < 432; i += 320) {
            float v = (i >= 4 && i < 404) ? xrow[i - 4] : 0.0f;
            _Float16 h = (_Float16)v;
            xa_s[i] = h;
            if (i > 0) xb_s[i - 1] = h;
        }
        if (tid == 0) xb_s[431] = (_Float16)0.0f;
        __syncthreads();

        // ---- conv1 via mfma_16x16x32_f16 -> y1T ----
        {
            const int lane = tid & 63;
            const int wv5  = tid >> 6;
            const int nl   = lane & 15;
            const int q    = lane >> 4;
            union { int4 v; f16x8 h; } a1;
            a1.v = *(const int4*)((const int*)w1T_s + nl * 16 + q * 4);
            float s1r[4], sh1r[4];
#pragma unroll
            for (int r = 0; r < 4; ++r) {
                s1r[r]  = cst_s[q * 4 + r];
                sh1r[r] = cst_s[16 + q * 4 + r];
            }
            const int* xsel = (const int*)((nl & 1) ? xb_s : xa_s);
            for (int tile = 0; tile < 5; ++tile) {
                const int t0 = (wv5 * 5 + tile) * 16;
                const int dw = (t0 + nl + q * 8) >> 1;
                union { int4 v; f16x8 h; } bf;
                bf.v.x = xsel[dw];
                bf.v.y = xsel[dw + 1];
                bf.v.z = xsel[dw + 2];
                bf.v.w = xsel[dw + 3];
                f32x4 acc = {0.0f, 0.0f, 0.0f, 0.0f};
                acc = __builtin_amdgcn_mfma_f32_16x16x32_f16(a1.h, bf.h, acc, 0, 0, 0);
                union { _Float16 h[4]; int2 d; } pk;
#pragma unroll
                for (int r = 0; r < 4; ++r) {
                    float v = acc[r] * s1r[r] + sh1r[r];
                    pk.h[r] = (_Float16)(v > 0.0f ? v : 0.0f);
                }
                int* yp = (int*)y1T_s + (t0 + nl + 3) * Y1T_STRIDE_I + q * 2;
                yp[0] = pk.d.x;
                yp[1] = pk.d.y;
            }
        }
        __syncthreads();

        // ---- conv2 MFMA (swapped operands) + scaled per-lane subseg max ----
        {
            const int wv    = tid >> 6;
            const int nlane = nlaneH;
            const int half  = halfH;

            for (int tile = wv; tile < 13; tile += 5) {
                const int tA  = tile * 32 + nlane;
                const int tAr = tA < 400 ? tA : 399;
                f32x16 acc;
#pragma unroll
                for (int i = 0; i < 16; ++i) acc[i] = 0.0f;

#pragma unroll
                for (int dt = 0; dt < 7; ++dt) {
                    const int* p = (const int*)y1T_s + (tAr + dt) * Y1T_STRIDE_I + half * 4;
                    union { int d[4]; f16x8 h; } bf;
                    bf.d[0] = p[0];
                    bf.d[1] = p[1];
                    bf.d[2] = p[2];
                    bf.d[3] = p[3];
                    acc = __builtin_amdgcn_mfma_f32_32x32x16_f16(bf.h, af[dt].h, acc, 0, 0, 0);
                }

                const int base = nlane * SEG_STRIDE + tile * 8 + half;
#pragma unroll
                for (int q = 0; q < 4; ++q) {
                    float v0 = acc[4 * q + 0] * s2f;
                    float v1 = acc[4 * q + 1] * s2f;
                    float v2 = acc[4 * q + 2] * s2f;
                    float v3 = acc[4 * q + 3] * s2f;
                    float m  = fmaxf(fmaxf(v0, v1), fmaxf(v2, v3));
                    const int sub = tile * 8 + 2 * q + half;
                    if (sub < 100) segmax_s[base + 2 * q] = (_Float16)m;
                }
            }
        }
        __syncthreads();

        // ---- pool(40) -> shift+relu -> featF (fragment-layout scatter) ----
        {
            const int f = tid & 31;
            const int p = tid >> 5;
            float m = -3.0e38f;
#pragma unroll
            for (int k = 0; k < 10; ++k)
                m = fmaxf(m, (float)segmax_s[f * SEG_STRIDE + p * 10 + k]);
            float v = fmaxf(m + sh2f, 0.0f);
            const int kl = f * 10 + p;            // k_local in [0,320)
            const int kh2 = (kl >= 160) ? 1 : 0;
            const int kr  = kl - kh2 * 160;
            const int s   = kr >> 4;
            const int ko  = kr & 15;
            const int addr = ((((c * 2 + kh2) * 10 + s) * 2 + (b >> 5)) * 64
                              + (ko >> 3) * 32 + (b & 31)) * 8 + (ko & 7);
            featF[addr] = (_Float16)v;
        }
    }
}

// ---------------------------------------------------------------------------
// FC1 (fragment path): 173 blocks x 512 threads. All operands pre-packed in
// fragment order -> every load is a coalesced b128 (1KB/wave-instr); no cvt.
// Wave w: kh=w>>2 (160k, 10 steps), jq=w&3. kh-halves combined via LDS,
// one fp32 atomicAdd per (j,b) per block into h (prep zeroes h).
// ---------------------------------------------------------------------------
__global__ __launch_bounds__(512) void fc1_frag_kernel(
    const _Float16* __restrict__ featF, const _Float16* __restrict__ afrag,
    float* __restrict__ h_ws)
{
    __shared__ float red[4 * 2048];

    const int tid   = threadIdx.x;
    const int c     = blockIdx.x;
    const int w     = tid >> 6;
    const int lane  = tid & 63;
    const int nlane = lane & 31;
    const int half  = lane >> 5;
    const int kh    = w >> 2;
    const int jq    = w & 3;

    const int4* Ap = (const int4*)afrag +
                     ((size_t)(c * 2 + kh) * 40 + jq) * 64 + lane;  // s-stride 256
    const int4* Bp = (const int4*)featF +
                     (size_t)(c * 2 + kh) * 1280 + lane;            // s-stride 128, g-stride 64

    f32x16 acc0, acc1;
#pragma unroll
    for (int i = 0; i < 16; ++i) { acc0[i] = 0.0f; acc1[i] = 0.0f; }

#pragma unroll
    for (int s = 0; s < 10; ++s) {
        union { int4 q; f16x8 h; } a, b0, b1;
        a.q  = Ap[s * 256];
        b0.q = Bp[s * 128];
        b1.q = Bp[s * 128 + 64];
        acc0 = __builtin_amdgcn_mfma_f32_32x32x16_f16(a.h, b0.h, acc0, 0, 0, 0);
        acc1 = __builtin_amdgcn_mfma_f32_32x32x16_f16(a.h, b1.h, acc1, 0, 0, 0);
    }

    if (kh == 1) {
        float* rp = red + jq * 2048;
#pragma unroll
        for (int reg = 0; reg < 16; ++reg) {
            rp[(reg * 2 + half) * 64 + nlane]      = acc0[reg];
            rp[(reg * 2 + half) * 64 + 32 + nlane] = acc1[reg];
        }
    }
    __syncthreads();
    if (kh == 0) {
        const float* rp = red + jq * 2048;
#pragma unroll
        for (int reg = 0; reg < 16; ++reg) {
            int j = jq * 32 + (reg & 3) + 8 * (reg >> 2) + 4 * half;
            float v0 = acc0[reg] + rp[(reg * 2 + half) * 64 + nlane];
            float v1 = acc1[reg] + rp[(reg * 2 + half) * 64 + 32 + nlane];
            atomicAdd(&h_ws[j * 64 + nlane], v0);
            atomicAdd(&h_ws[j * 64 + 32 + nlane], v1);
        }
    }
}

// ---------------------------------------------------------------------------
// FC1 fallback (ws too small for afrag): gathered fp32 wc1 A (R6-style) +
// coalesced featF B. Used only when ws_size < 22,774,656.
// ---------------------------------------------------------------------------
__global__ __launch_bounds__(512) void fc1_fb_kernel(
    const _Float16* __restrict__ featF, const float* __restrict__ wc1,
    float* __restrict__ h_ws)
{
    __shared__ float red[4 * 2048];

    const int tid   = threadIdx.x;
    const int c     = blockIdx.x;
    const int w     = tid >> 6;
    const int lane  = tid & 63;
    const int nlane = lane & 31;
    const int half  = lane >> 5;
    const int kh    = w >> 2;
    const int jq    = w & 3;
    const int jrow  = jq * 32 + nlane;

    const float* ap = wc1 + (size_t)jrow * KFEAT + c * 320 + kh * 160 + half * 8;
    const int4*  Bp = (const int4*)featF + (size_t)(c * 2 + kh) * 1280 + lane;

    f32x16 acc0, acc1;
#pragma unroll
    for (int i = 0; i < 16; ++i) { acc0[i] = 0.0f; acc1[i] = 0.0f; }

#pragma unroll 5
    for (int s = 0; s < 10; ++s) {
        const float4 aw0 = *(const float4*)(ap + s * 16);
        const float4 aw1 = *(const float4*)(ap + s * 16 + 4);
        union { fp16x2 v2[4]; f16x8 h; } a;
        a.v2[0] = __builtin_amdgcn_cvt_pkrtz(aw0.x, aw0.y);
        a.v2[1] = __builtin_amdgcn_cvt_pkrtz(aw0.z, aw0.w);
        a.v2[2] = __builtin_amdgcn_cvt_pkrtz(aw1.x, aw1.y);
        a.v2[3] = __builtin_amdgcn_cvt_pkrtz(aw1.z, aw1.w);

        union { int4 q; f16x8 h; } b0, b1;
        b0.q = Bp[s * 128];
        b1.q = Bp[s * 128 + 64];

        acc0 = __builtin_amdgcn_mfma_f32_32x32x16_f16(a.h, b0.h, acc0, 0, 0, 0);
        acc1 = __builtin_amdgcn_mfma_f32_32x32x16_f16(a.h, b1.h, acc1, 0, 0, 0);
    }

    if (kh == 1) {
        float* rp = red + jq * 2048;
#pragma unroll
        for (int reg = 0; reg < 16; ++reg) {
            rp[(reg * 2 + half) * 64 + nlane]      = acc0[reg];
            rp[(reg * 2 + half) * 64 + 32 + nlane] = acc1[reg];
        }
    }
    __syncthreads();
    if (kh == 0) {
        const float* rp = red + jq * 2048;
#pragma unroll
        for (int reg = 0; reg < 16; ++reg) {
            int j = jq * 32 + (reg & 3) + 8 * (reg >> 2) + 4 * half;
            float v0 = acc0[reg] + rp[(reg * 2 + half) * 64 + nlane];
            float v1 = acc1[reg] + rp[(reg * 2 + half) * 64 + 32 + nlane];
            atomicAdd(&h_ws[j * 64 + nlane], v0);
            atomicAdd(&h_ws[j * 64 + 32 + nlane], v1);
        }
    }
}

// ---------------------------------------------------------------------------
// FC2: one block, 512 threads. b = t&63 (coalesced h reads), j chunked 8-way.
// ---------------------------------------------------------------------------
__global__ __launch_bounds__(512) void fc2_kernel(
    const float* __restrict__ h_ws, const float* __restrict__ bc1,
    const float* __restrict__ wc2, const float* __restrict__ bc2,
    float* __restrict__ out)
{
    __shared__ float partial[512];
    const int t  = threadIdx.x;
    const int b  = t & 63;
    const int jc = t >> 6;
    float s = 0.0f;
#pragma unroll
    for (int jj = 0; jj < 16; ++jj) {
        const int j = jc * 16 + jj;
        float hv = h_ws[j * 64 + b] + bc1[j];
        hv = hv > 0.0f ? hv : 0.0f;
        s += wc2[j] * hv;
    }
    partial[t] = s;
    __syncthreads();
    if (t < 64) {
        float r = partial[t];
#pragma unroll
        for (int k = 1; k < 8; ++k) r += partial[t + 64 * k];
        out[b] = r + bc2[0];
    }
}

extern "C" void kernel_launch(void* const* d_in, const int* in_sizes, int n_in,
                              void* d_out, int out_size, void* d_ws, size_t ws_size,
                              hipStream_t stream)
{
    const float* x     = (const float*)d_in[0];
    const float* w1    = (const float*)d_in[1];
    const float* b1    = (const float*)d_in[2];
    const float* g1    = (const float*)d_in[3];
    const float* beta1 = (const float*)d_in[4];
    const float* m1    = (const float*)d_in[5];
    const float* v1    = (const float*)d_in[6];
    const float* w2    = (const float*)d_in[7];
    const float* b2    = (const float*)d_in[8];
    const float* g2    = (const float*)d_in[9];
    const float* beta2 = (const float*)d_in[10];
    const float* m2    = (const float*)d_in[11];
    const float* v2    = (const float*)d_in[12];
    const float* wc1   = (const float*)d_in[13];
    const float* bc1   = (const float*)d_in[14];
    const float* wc2   = (const float*)d_in[15];
    const float* bc2   = (const float*)d_in[16];

    char* ws = (char*)d_ws;
    _Float16* featF = (_Float16*)ws;                          // 7,086,080 B
    _Float16* w2T_g = (_Float16*)(ws + 7086080);              // 1,240,064 B
    _Float16* w1T_g = (_Float16*)(ws + 8326144);              // 177,152 B
    float*    sc_g  = (float*)(ws + 8503296);                 // 66,432 B
    float*    h_ws  = (float*)(ws + 8569728);                 // 32,768 B
    _Float16* afrag = (_Float16*)(ws + 8602496);              // 14,172,160 B -> end 22,774,656

    const int useFrag = (ws_size >= (size_t)22774656) ? 1 : 0;

    // PREP_BASE + NA4 = 1,619,168 -> 6325 blocks of 256 (afrag tail skipped
    // when !useFrag; harmless extra blocks otherwise identical).
    hipLaunchKernelGGL(prep_kernel, dim3(useFrag ? 6325 : 2865), dim3(256), 0, stream,
                       w1, b1, g1, beta1, m1, v1,
                       w2, b2, g2, beta2, m2, v2, wc1,
                       w2T_g, w1T_g, sc_g, h_ws, afrag, useFrag);

    hipLaunchKernelGGL(tower_kernel, dim3(C_CH, 16), dim3(320), 0, stream,
                       x, w2T_g, w1T_g, sc_g, featF);

    if (useFrag) {
        hipLaunchKernelGGL(fc1_frag_kernel, dim3(173), dim3(512), 0, stream,
                           featF, afrag, h_ws);
    } else {
        hipLaunchKernelGGL(fc1_fb_kernel, dim3(173), dim3(512), 0, stream,
                           featF, wc1, h_ws);
    }

    hipLaunchKernelGGL(fc2_kernel, dim3(1), dim3(512), 0, stream,
                       h_ws, bc1, wc2, bc2, (float*)d_out);
}

// Round 9
// 199.619 us; speedup vs baseline: 1.0003x; 1.0003x over previous
//
#include <hip/hip_runtime.h>

#define C_CH 173
#define L_IN 400
#define EPSV 1e-5f
#define KFEAT 55360  // C*32*10

typedef __fp16   fp16x2 __attribute__((ext_vector_type(2)));
typedef _Float16 f16x8  __attribute__((ext_vector_type(8)));
typedef float    f32x4  __attribute__((ext_vector_type(4)));
typedef float    f32x16 __attribute__((ext_vector_type(16)));

// y1T row: 16 f16 + 1 pad dword = 9 dwords (R2/R3/R7-proven, conflict-free).
#define Y1T_STRIDE_I 9
#define Y1T_ROWS   406  // row r = y1 time t+3; rows 0..2, 403..405 zeroed halo

// segmax: [f][sub], sub = 0..99. Stride 102 f16 = 51 dwords (R3-proven).
#define SEG_STRIDE 102

// ---------------------------------------------------------------------------
// Tower kernel (R9: prep FUSED — 2-kernel pipeline; tails across R4-R8
// clustered at ~115-123us regardless of fc1 structure => per-launch fixed
// cost ~12-15us dominates the tail; kernel count is the lever).
// Main loop is R7-EXACT (70.5us, best known). Staging now gather-transforms
// this block's channel weights straight from the raw inputs into LDS:
//   w2T_s[dt*512+f*16+g] = w2[c*3584+f*112+g*7+dt]   (w2 = 2.4MB, L2-res)
//   w1T_s[g*32+k]        = k<9 ? w1[c*144+g*9+k] : 0
//   cst_s[96]            = BN scale/shift (rsqrtf)
// 16x per-c redundancy (16 batch-groups) ~= 40MB of L2-hit reads ~= +3us,
// vs killing a whole prep launch. h/cnt zeroed by the blockIdx.y==0 slice
// (stream order guarantees completion before fc1's atomics).
// ---------------------------------------------------------------------------
__global__ __launch_bounds__(320, 7) void tower_kernel(
    const float* __restrict__ x,
    const float* __restrict__ w1, const float* __restrict__ b1,
    const float* __restrict__ g1, const float* __restrict__ beta1,
    const float* __restrict__ m1, const float* __restrict__ v1,
    const float* __restrict__ w2, const float* __restrict__ b2,
    const float* __restrict__ g2, const float* __restrict__ beta2,
    const float* __restrict__ m2, const float* __restrict__ v2,
    _Float16* __restrict__ featH, float* __restrict__ h_ws,
    unsigned int* __restrict__ cnt)
{
    __shared__ __align__(16) _Float16 xa_s[432];             // xa[i] = x_s[i]
    __shared__ __align__(16) _Float16 xb_s[432];             // xb[i] = x_s[i+1]
    __shared__ __align__(16) _Float16 w1T_s[16 * 32];        // [g][k]
    __shared__ __align__(16) _Float16 y1T_s[Y1T_ROWS * 2 * Y1T_STRIDE_I];
    __shared__ __align__(16) _Float16 w2T_s[7 * 512];        // [dt][f][g]
    __shared__ _Float16               segmax_s[32 * SEG_STRIDE]; // [f][sub]
    __shared__ __align__(16) float    cst_s[96];  // s1[16] sh1[16] s2[32] sh2[32]

    const int c   = blockIdx.x;
    const int tid = threadIdx.x;

    // ---- once-per-block staging: fused weight transform (was prep kernel) --
    {
        const float* w2c = w2 + (size_t)c * 3584;
        for (int i = tid; i < 3584; i += 320) {
            int dt = i >> 9, fg = i & 511;
            int f = fg >> 4, g = fg & 15;
            w2T_s[i] = (_Float16)w2c[f * 112 + g * 7 + dt];
        }
        const float* w1c = w1 + c * 144;
        for (int i = tid; i < 512; i += 320) {
            int g = i >> 5, k = i & 31;
            w1T_s[i] = (k < 9) ? (_Float16)w1c[g * 9 + k] : (_Float16)0.0f;
        }
        if (tid < 96) {
            int r = tid;
            float o;
            if (r < 32) {
                int cf = c * 16 + (r & 15);
                float inv = g1[cf] * rsqrtf(v1[cf] + EPSV);
                o = (r < 16) ? inv : (b1[cf] - m1[cf]) * inv + beta1[cf];
            } else {
                int cf = c * 32 + ((r - 32) & 31);
                float inv = g2[cf] * rsqrtf(v2[cf] + EPSV);
                o = (r < 64) ? inv : (b2[cf] - m2[cf]) * inv + beta2[cf];
            }
            cst_s[r] = o;
        }
        // zero y1T halo rows 0..2 and 403..405 (6 rows x 9 dwords)
        if (tid >= 96 && tid < 150) {
            int i = tid - 96;
            int r = i / 9, cx = i - r * 9;
            int row = (r < 3) ? r : (400 + r);
            ((int*)y1T_s)[row * Y1T_STRIDE_I + cx] = 0;
        }
        // zero the fc1 h-accumulator + semaphore (one block-slice does it;
        // completes before fc1 launches — same stream).
        if (blockIdx.y == 0) {
            if (c < 32 && tid < 256) h_ws[c * 256 + tid] = 0.0f;
            if (c == 32 && tid == 0)  cnt[0] = 0u;
        }
    }
    __syncthreads();
    // per-lane BN consts for conv2/pool (f = tid&31 in both scopes)
    const float s2f  = cst_s[32 + (tid & 31)];
    const float sh2f = cst_s[64 + (tid & 31)];

    // ---- hoisted conv2 weight fragments (loop-invariant across batches) ----
    const int nlaneH = tid & 31;
    const int halfH  = (tid >> 5) & 1;
    union F8q { int4 q; f16x8 h; } af[7];
#pragma unroll
    for (int dt = 0; dt < 7; ++dt)
        af[dt].q = *(const int4*)((const int*)w2T_s + dt * 256 + nlaneH * 8 + halfH * 4);

    for (int nb = 0; nb < 4; ++nb) {
        const int b = blockIdx.y * 4 + nb;

        // ---- stage x as f16 parity copies ----
        const float* xrow = x + ((size_t)b * C_CH + c) * L_IN;
        for (int i = tid; i < 432; i += 320) {
            float v = (i >= 4 && i < 404) ? xrow[i - 4] : 0.0f;
            _Float16 h = (_Float16)v;
            xa_s[i] = h;
            if (i > 0) xb_s[i - 1] = h;
        }
        if (tid == 0) xb_s[431] = (_Float16)0.0f;
        __syncthreads();

        // ---- conv1 via mfma_16x16x32_f16 -> y1T ----
        // A[m=g][k]=w1T; B[k][n]=x_s[t0+n+k-4] (+4 shift folded into x_s).
        {
            const int lane = tid & 63;
            const int wv5  = tid >> 6;
            const int nl   = lane & 15;
            const int q    = lane >> 4;
            union { int4 v; f16x8 h; } a1;
            a1.v = *(const int4*)((const int*)w1T_s + nl * 16 + q * 4);
            float s1r[4], sh1r[4];
#pragma unroll
            for (int r = 0; r < 4; ++r) {
                s1r[r]  = cst_s[q * 4 + r];
                sh1r[r] = cst_s[16 + q * 4 + r];
            }
            const int* xsel = (const int*)((nl & 1) ? xb_s : xa_s);
            for (int tile = 0; tile < 5; ++tile) {
                const int t0 = (wv5 * 5 + tile) * 16;
                const int dw = (t0 + nl + q * 8) >> 1;
                union { int4 v; f16x8 h; } bf;
                bf.v.x = xsel[dw];
                bf.v.y = xsel[dw + 1];
                bf.v.z = xsel[dw + 2];
                bf.v.w = xsel[dw + 3];
                f32x4 acc = {0.0f, 0.0f, 0.0f, 0.0f};
                acc = __builtin_amdgcn_mfma_f32_16x16x32_f16(a1.h, bf.h, acc, 0, 0, 0);
                union { _Float16 h[4]; int2 d; } pk;
#pragma unroll
                for (int r = 0; r < 4; ++r) {
                    float v = acc[r] * s1r[r] + sh1r[r];
                    pk.h[r] = (_Float16)(v > 0.0f ? v : 0.0f);
                }
                // stride-9 rows are only 4B aligned: two b32 stores
                int* yp = (int*)y1T_s + (t0 + nl + 3) * Y1T_STRIDE_I + q * 2;
                yp[0] = pk.d.x;
                yp[1] = pk.d.y;
            }
        }
        __syncthreads();

        // ---- conv2 MFMA (swapped operands) + scaled per-lane subseg max ----
        // acc = D[t][f]: f = lane&31, t = t0 + (reg&3) + 8*(reg>>2) + 4*half.
        {
            const int wv    = tid >> 6;
            const int nlane = nlaneH;
            const int half  = halfH;

            for (int tile = wv; tile < 13; tile += 5) {
                const int tA  = tile * 32 + nlane;
                const int tAr = tA < 400 ? tA : 399;   // clamp; bad rows discarded
                f32x16 acc;
#pragma unroll
                for (int i = 0; i < 16; ++i) acc[i] = 0.0f;

#pragma unroll
                for (int dt = 0; dt < 7; ++dt) {
                    const int* p = (const int*)y1T_s + (tAr + dt) * Y1T_STRIDE_I + half * 4;
                    union { int d[4]; f16x8 h; } bf;
                    bf.d[0] = p[0];
                    bf.d[1] = p[1];
                    bf.d[2] = p[2];
                    bf.d[3] = p[3];
                    acc = __builtin_amdgcn_mfma_f32_32x32x16_f16(bf.h, af[dt].h, acc, 0, 0, 0);
                }

                const int base = nlane * SEG_STRIDE + tile * 8 + half;
#pragma unroll
                for (int q = 0; q < 4; ++q) {
                    // scale per element (sign-safe wrt g2), defer shift+relu
                    float v0 = acc[4 * q + 0] * s2f;
                    float v1 = acc[4 * q + 1] * s2f;
                    float v2 = acc[4 * q + 2] * s2f;
                    float v3 = acc[4 * q + 3] * s2f;
                    float m  = fmaxf(fmaxf(v0, v1), fmaxf(v2, v3));
                    const int sub = tile * 8 + 2 * q + half;
                    if (sub < 100) segmax_s[base + 2 * q] = (_Float16)m;
                }
            }
        }
        __syncthreads();

        // ---- pool(40) = max of 10 subseg-maxes; apply shift + relu ----
        {
            const int f = tid & 31;
            const int p = tid >> 5;
            float m = -3.0e38f;
#pragma unroll
            for (int k = 0; k < 10; ++k)
                m = fmaxf(m, (float)segmax_s[f * SEG_STRIDE + p * 10 + k]);
            float v = fmaxf(m + sh2f, 0.0f);
            featH[(size_t)b * KFEAT + (c * 32 + f) * 10 + p] = (_Float16)v;
        }
        // no trailing sync needed (R2-proven): next x-stage touches xa/xb
        // only; segmax(i) fully consumed before the next post-stage sync;
        // y1T rewritten only after the post-stage sync.
    }
}

// ---------------------------------------------------------------------------
// FC1 + fused FC2 (R9). fc1 body = R6-exact (passed 3x): 173 blocks x 512
// threads; wave w: kh=w>>2 (160k, 10 steps), jq=w&3; kh-halves combined via
// LDS; fp32 atomicAdd into h (tower zeroed it).
// FC2 fusion: split-K semaphore. __syncthreads() drains vmcnt -> this
// block's h-atomics are globally performed; tid0 threadfence + agent-scope
// fetch_add on cnt; the 173rd arriver re-reads h with agent-scope atomic
// loads (bypass stale L1/L2 across XCDs) and computes out[64].
// ---------------------------------------------------------------------------
__global__ __launch_bounds__(512) void fc1_kernel(
    const _Float16* __restrict__ featH, const float* __restrict__ wc1,
    const float* __restrict__ bc1, const float* __restrict__ wc2,
    const float* __restrict__ bc2,
    float* __restrict__ h_ws, unsigned int* __restrict__ cnt,
    float* __restrict__ out)
{
    __shared__ float red[4 * 2048];
    __shared__ unsigned int isLast;

    const int tid   = threadIdx.x;
    const int w     = tid >> 6;
    const int lane  = tid & 63;
    const int nlane = lane & 31;
    const int half  = lane >> 5;
    const int kh    = w >> 2;
    const int jq    = w & 3;
    const int jrow  = jq * 32 + nlane;
    const int k0    = blockIdx.x * 320 + kh * 160;

    const float*    ap  = wc1   + (size_t)jrow * KFEAT + k0 + half * 8;
    const _Float16* b0p = featH + (size_t)nlane * KFEAT + k0 + half * 8;
    const _Float16* b1p = featH + (size_t)(nlane + 32) * KFEAT + k0 + half * 8;

    f32x16 acc0, acc1;
#pragma unroll
    for (int i = 0; i < 16; ++i) { acc0[i] = 0.0f; acc1[i] = 0.0f; }

#pragma unroll 5
    for (int s = 0; s < 10; ++s) {
        const float4 aw0 = *(const float4*)(ap + s * 16);
        const float4 aw1 = *(const float4*)(ap + s * 16 + 4);
        union { fp16x2 v2[4]; f16x8 h; } a;
        a.v2[0] = __builtin_amdgcn_cvt_pkrtz(aw0.x, aw0.y);
        a.v2[1] = __builtin_amdgcn_cvt_pkrtz(aw0.z, aw0.w);
        a.v2[2] = __builtin_amdgcn_cvt_pkrtz(aw1.x, aw1.y);
        a.v2[3] = __builtin_amdgcn_cvt_pkrtz(aw1.z, aw1.w);

        union { int4 q; f16x8 h; } b0, b1;
        b0.q = *(const int4*)(b0p + s * 16);
        b1.q = *(const int4*)(b1p + s * 16);

        acc0 = __builtin_amdgcn_mfma_f32_32x32x16_f16(a.h, b0.h, acc0, 0, 0, 0);
        acc1 = __builtin_amdgcn_mfma_f32_32x32x16_f16(a.h, b1.h, acc1, 0, 0, 0);
    }

    if (kh == 1) {
        float* rp = red + jq * 2048;
#pragma unroll
        for (int reg = 0; reg < 16; ++reg) {
            rp[(reg * 2 + half) * 64 + nlane]      = acc0[reg];
            rp[(reg * 2 + half) * 64 + 32 + nlane] = acc1[reg];
        }
    }
    __syncthreads();
    if (kh == 0) {
        const float* rp = red + jq * 2048;
#pragma unroll
        for (int reg = 0; reg < 16; ++reg) {
            int j = jq * 32 + (reg & 3) + 8 * (reg >> 2) + 4 * half;
            float v0 = acc0[reg] + rp[(reg * 2 + half) * 64 + nlane];
            float v1 = acc1[reg] + rp[(reg * 2 + half) * 64 + 32 + nlane];
            atomicAdd(&h_ws[j * 64 + nlane], v0);
            atomicAdd(&h_ws[j * 64 + 32 + nlane], v1);
        }
    }

    // ---- split-K semaphore: last block to finish does FC2 ----
    __syncthreads();   // drains vmcnt -> this block's atomics are performed
    if (tid == 0) {
        __threadfence();
        unsigned int old = __hip_atomic_fetch_add(
            cnt, 1u, __ATOMIC_ACQ_REL, __HIP_MEMORY_SCOPE_AGENT);
        isLast = (old == (unsigned int)(C_CH - 1)) ? 1u : 0u;
    }
    __syncthreads();   // isLast is block-uniform after this
    if (isLast) {
        __threadfence();
        const int b  = tid & 63;
        const int jc = tid >> 6;
        float s = 0.0f;
#pragma unroll
        for (int jj = 0; jj < 16; ++jj) {
            const int j = jc * 16 + jj;
            float hv = __hip_atomic_load(&h_ws[j * 64 + b],
                                         __ATOMIC_RELAXED,
                                         __HIP_MEMORY_SCOPE_AGENT) + bc1[j];
            hv = hv > 0.0f ? hv : 0.0f;
            s += wc2[j] * hv;
        }
        red[tid] = s;
        __syncthreads();
        if (tid < 64) {
            float r = red[tid];
#pragma unroll
            for (int k = 1; k < 8; ++k) r += red[tid + 64 * k];
            out[tid] = r + bc2[0];
        }
    }
}

extern "C" void kernel_launch(void* const* d_in, const int* in_sizes, int n_in,
                              void* d_out, int out_size, void* d_ws, size_t ws_size,
                              hipStream_t stream)
{
    const float* x     = (const float*)d_in[0];
    const float* w1    = (const float*)d_in[1];
    const float* b1    = (const float*)d_in[2];
    const float* g1    = (const float*)d_in[3];
    const float* beta1 = (const float*)d_in[4];
    const float* m1    = (const float*)d_in[5];
    const float* v1    = (const float*)d_in[6];
    const float* w2    = (const float*)d_in[7];
    const float* b2    = (const float*)d_in[8];
    const float* g2    = (const float*)d_in[9];
    const float* beta2 = (const float*)d_in[10];
    const float* m2    = (const float*)d_in[11];
    const float* v2    = (const float*)d_in[12];
    const float* wc1   = (const float*)d_in[13];
    const float* bc1   = (const float*)d_in[14];
    const float* wc2   = (const float*)d_in[15];
    const float* bc2   = (const float*)d_in[16];

    char* ws = (char*)d_ws;
    _Float16*     featH = (_Float16*)ws;                      // 7,086,080 B
    float*        h_ws  = (float*)(ws + 7086080);             // 32,768 B
    unsigned int* cnt   = (unsigned int*)(ws + 7118848);      // 4 B

    hipLaunchKernelGGL(tower_kernel, dim3(C_CH, 16), dim3(320), 0, stream,
                       x, w1, b1, g1, beta1, m1, v1,
                       w2, b2, g2, beta2, m2, v2,
                       featH, h_ws, cnt);

    hipLaunchKernelGGL(fc1_kernel, dim3(C_CH), dim3(512), 0, stream,
                       featH, wc1, bc1, wc2, bc2, h_ws, cnt, (float*)d_out);
}

// Round 10
// 196.775 us; speedup vs baseline: 1.0148x; 1.0145x over previous
//
#include <hip/hip_runtime.h>

#define C_CH 173
#define L_IN 400
#define EPSV 1e-5f
#define KFEAT 55360  // C*32*10

typedef __fp16   fp16x2 __attribute__((ext_vector_type(2)));
typedef _Float16 f16x8  __attribute__((ext_vector_type(8)));
typedef float    f32x4  __attribute__((ext_vector_type(4)));
typedef float    f32x16 __attribute__((ext_vector_type(16)));

// y1T row: 16 f16 + 1 pad dword = 9 dwords (R2/R3/R7-proven, conflict-free).
#define Y1T_STRIDE_I 9
#define Y1T_ROWS   406  // row r = y1 time t+3; rows 0..2, 403..405 zeroed halo

// segmax: [f][sub], sub = 0..99. Stride 102 f16 = 51 dwords (R3-proven).
#define SEG_STRIDE 102

#define N1 (173 * 3584)  // w2T elems
#define N2 (173 * 512)   // w1T elems
#define N3 (173 * 96)    // BN consts per c

// ---------------------------------------------------------------------------
// Prep kernel (R7-exact; h-zeroing dropped — reduce now overwrites h).
//  w2T_g[c][dt*512 + f*16 + g] f16 ; w1T_g[c][g*32+k] f16 (k>=9 zero)
//  sc_g[c*96 + r]: r<16 scale1 | r<32 shift1 | r<64 scale2 | r<96 shift2
// ---------------------------------------------------------------------------
__global__ __launch_bounds__(256) void prep_kernel(
    const float* __restrict__ w1, const float* __restrict__ b1,
    const float* __restrict__ g1, const float* __restrict__ beta1,
    const float* __restrict__ m1, const float* __restrict__ v1,
    const float* __restrict__ w2, const float* __restrict__ b2,
    const float* __restrict__ g2, const float* __restrict__ beta2,
    const float* __restrict__ m2, const float* __restrict__ v2,
    _Float16* __restrict__ w2T_g, _Float16* __restrict__ w1T_g,
    float* __restrict__ sc_g)
{
    const int idx = blockIdx.x * 256 + threadIdx.x;
    if (idx < N1) {
        int c = idx / 3584, r = idx - c * 3584;
        int dt = r >> 9, fg = r & 511;
        int f = fg >> 4, g = fg & 15;
        w2T_g[idx] = (_Float16)w2[c * 3584 + f * 112 + g * 7 + dt];
    } else if (idx < N1 + N2) {
        int j = idx - N1;
        int c = j / 512, r = j - c * 512;
        int g = r >> 5, k = r & 31;
        w1T_g[j] = (k < 9) ? (_Float16)w1[c * 144 + g * 9 + k] : (_Float16)0.0f;
    } else if (idx < N1 + N2 + N3) {
        int j = idx - N1 - N2;
        int c = j / 96, r = j - c * 96;
        float o;
        if (r < 32) {
            int g  = r & 15;
            int cf = c * 16 + g;
            float inv = g1[cf] * rsqrtf(v1[cf] + EPSV);
            o = (r < 16) ? inv : (b1[cf] - m1[cf]) * inv + beta1[cf];
        } else {
            int f  = (r - 32) & 31;
            int cf = c * 32 + f;
            float inv = g2[cf] * rsqrtf(v2[cf] + EPSV);
            o = (r < 64) ? inv : (b2[cf] - m2[cf]) * inv + beta2[cf];
        }
        sc_g[j] = o;
    }
}

// ---------------------------------------------------------------------------
// Tower kernel: R7-EXACT (70.5us, 3x verified). One block per (c, batch-
// group of 4). 320 threads = 5 waves. conv2: A=y1 (time rows), B=w2 (f
// lanes) -> per-lane register pool max; af[7] hoisted to block scope.
// ---------------------------------------------------------------------------
__global__ __launch_bounds__(320, 7) void tower_kernel(
    const float* __restrict__ x,
    const _Float16* __restrict__ w2T_g, const _Float16* __restrict__ w1T_g,
    const float* __restrict__ sc_g,
    _Float16* __restrict__ featH)
{
    __shared__ __align__(16) _Float16 xa_s[432];             // xa[i] = x_s[i]
    __shared__ __align__(16) _Float16 xb_s[432];             // xb[i] = x_s[i+1]
    __shared__ __align__(16) _Float16 w1T_s[16 * 32];        // [g][k]
    __shared__ __align__(16) _Float16 y1T_s[Y1T_ROWS * 2 * Y1T_STRIDE_I];
    __shared__ __align__(16) _Float16 w2T_s[7 * 512];        // [dt][f][g]
    __shared__ _Float16               segmax_s[32 * SEG_STRIDE]; // [f][sub]
    __shared__ __align__(16) float    cst_s[96];  // s1[16] sh1[16] s2[32] sh2[32]

    const int c   = blockIdx.x;
    const int tid = threadIdx.x;

    // ---- once-per-block staging (coalesced, no div/cvt/scatter) ----
    {
        const int4* w2src = (const int4*)(w2T_g + (size_t)c * 3584);
        for (int i = tid; i < 448; i += 320) ((int4*)w2T_s)[i] = w2src[i];
        const int4* w1src = (const int4*)(w1T_g + c * 512);
        if (tid < 64) ((int4*)w1T_s)[tid] = w1src[tid];
        const float4* csrc = (const float4*)(sc_g + c * 96);
        if (tid >= 64 && tid < 88) ((float4*)cst_s)[tid - 64] = csrc[tid - 64];
        // zero y1T halo rows 0..2 and 403..405 (6 rows x 9 dwords)
        if (tid >= 88 && tid < 142) {
            int i = tid - 88;
            int r = i / 9, cx = i - r * 9;
            int row = (r < 3) ? r : (400 + r);
            ((int*)y1T_s)[row * Y1T_STRIDE_I + cx] = 0;
        }
    }
    __syncthreads();
    // per-lane BN consts for conv2/pool (f = tid&31 in both scopes)
    const float s2f  = cst_s[32 + (tid & 31)];
    const float sh2f = cst_s[64 + (tid & 31)];

    // ---- hoisted conv2 weight fragments (loop-invariant across batches) ----
    const int nlaneH = tid & 31;
    const int halfH  = (tid >> 5) & 1;
    union F8q { int4 q; f16x8 h; } af[7];
#pragma unroll
    for (int dt = 0; dt < 7; ++dt)
        af[dt].q = *(const int4*)((const int*)w2T_s + dt * 256 + nlaneH * 8 + halfH * 4);

    for (int nb = 0; nb < 4; ++nb) {
        const int b = blockIdx.y * 4 + nb;

        // ---- stage x as f16 parity copies ----
        const float* xrow = x + ((size_t)b * C_CH + c) * L_IN;
        for (int i = tid; i < 432; i += 320) {
            float v = (i >= 4 && i < 404) ? xrow[i - 4] : 0.0f;
            _Float16 h = (_Float16)v;
            xa_s[i] = h;
            if (i > 0) xb_s[i - 1] = h;
        }
        if (tid == 0) xb_s[431] = (_Float16)0.0f;
        __syncthreads();

        // ---- conv1 via mfma_16x16x32_f16 -> y1T ----
        // A[m=g][k]=w1T; B[k][n]=x_s[t0+n+k-4] (+4 shift folded into x_s).
        {
            const int lane = tid & 63;
            const int wv5  = tid >> 6;
            const int nl   = lane & 15;
            const int q    = lane >> 4;
            union { int4 v; f16x8 h; } a1;
            a1.v = *(const int4*)((const int*)w1T_s + nl * 16 + q * 4);
            float s1r[4], sh1r[4];
#pragma unroll
            for (int r = 0; r < 4; ++r) {
                s1r[r]  = cst_s[q * 4 + r];
                sh1r[r] = cst_s[16 + q * 4 + r];
            }
            const int* xsel = (const int*)((nl & 1) ? xb_s : xa_s);
            for (int tile = 0; tile < 5; ++tile) {
                const int t0 = (wv5 * 5 + tile) * 16;
                const int dw = (t0 + nl + q * 8) >> 1;
                union { int4 v; f16x8 h; } bf;
                bf.v.x = xsel[dw];
                bf.v.y = xsel[dw + 1];
                bf.v.z = xsel[dw + 2];
                bf.v.w = xsel[dw + 3];
                f32x4 acc = {0.0f, 0.0f, 0.0f, 0.0f};
                acc = __builtin_amdgcn_mfma_f32_16x16x32_f16(a1.h, bf.h, acc, 0, 0, 0);
                union { _Float16 h[4]; int2 d; } pk;
#pragma unroll
                for (int r = 0; r < 4; ++r) {
                    float v = acc[r] * s1r[r] + sh1r[r];
                    pk.h[r] = (_Float16)(v > 0.0f ? v : 0.0f);
                }
                // stride-9 rows are only 4B aligned: two b32 stores
                int* yp = (int*)y1T_s + (t0 + nl + 3) * Y1T_STRIDE_I + q * 2;
                yp[0] = pk.d.x;
                yp[1] = pk.d.y;
            }
        }
        __syncthreads();

        // ---- conv2 MFMA (swapped operands) + scaled per-lane subseg max ----
        // acc = D[t][f]: f = lane&31, t = t0 + (reg&3) + 8*(reg>>2) + 4*half.
        {
            const int wv    = tid >> 6;
            const int nlane = nlaneH;
            const int half  = halfH;

            for (int tile = wv; tile < 13; tile += 5) {
                const int tA  = tile * 32 + nlane;
                const int tAr = tA < 400 ? tA : 399;   // clamp; bad rows discarded
                f32x16 acc;
#pragma unroll
                for (int i = 0; i < 16; ++i) acc[i] = 0.0f;

#pragma unroll
                for (int dt = 0; dt < 7; ++dt) {
                    const int* p = (const int*)y1T_s + (tAr + dt) * Y1T_STRIDE_I + half * 4;
                    union { int d[4]; f16x8 h; } bf;
                    bf.d[0] = p[0];
                    bf.d[1] = p[1];
                    bf.d[2] = p[2];
                    bf.d[3] = p[3];
                    acc = __builtin_amdgcn_mfma_f32_32x32x16_f16(bf.h, af[dt].h, acc, 0, 0, 0);
                }

                const int base = nlane * SEG_STRIDE + tile * 8 + half;
#pragma unroll
                for (int q = 0; q < 4; ++q) {
                    // scale per element (sign-safe wrt g2), defer shift+relu
                    float v0 = acc[4 * q + 0] * s2f;
                    float v1 = acc[4 * q + 1] * s2f;
                    float v2 = acc[4 * q + 2] * s2f;
                    float v3 = acc[4 * q + 3] * s2f;
                    float m  = fmaxf(fmaxf(v0, v1), fmaxf(v2, v3));
                    const int sub = tile * 8 + 2 * q + half;
                    if (sub < 100) segmax_s[base + 2 * q] = (_Float16)m;
                }
            }
        }
        __syncthreads();

        // ---- pool(40) = max of 10 subseg-maxes; apply shift + relu ----
        {
            const int f = tid & 31;
            const int p = tid >> 5;
            float m = -3.0e38f;
#pragma unroll
            for (int k = 0; k < 10; ++k)
                m = fmaxf(m, (float)segmax_s[f * SEG_STRIDE + p * 10 + k]);
            float v = fmaxf(m + sh2f, 0.0f);
            featH[(size_t)b * KFEAT + (c * 32 + f) * 10 + p] = (_Float16)v;
        }
        // no trailing sync needed: next iter's x-stage touches xa/xb only;
        // segmax(i) is fully consumed before any wave passes the next
        // post-stage sync; y1T rewritten only after the post-stage sync.
    }
}

// ---------------------------------------------------------------------------
// FC1 (R10): R6-proven MFMA body (173 blocks x 512 threads, kh split via
// LDS) but ends with COALESCED DISJOINT STORES to part[kb][8192] instead of
// atomicAdd. R9 inference: fc1 ~75us was the 1.42M same-line device-scope
// fp32 atomics (2768 adds per 64B line, serialized at the cross-XCD
// coherence point) — disjoint stores remove that entirely.
// ---------------------------------------------------------------------------
__global__ __launch_bounds__(512) void fc1_kernel(
    const _Float16* __restrict__ featH, const float* __restrict__ wc1,
    float* __restrict__ part)
{
    __shared__ float red[4 * 2048];

    const int tid   = threadIdx.x;
    const int kb    = blockIdx.x;
    const int w     = tid >> 6;
    const int lane  = tid & 63;
    const int nlane = lane & 31;
    const int half  = lane >> 5;
    const int kh    = w >> 2;
    const int jq    = w & 3;
    const int jrow  = jq * 32 + nlane;
    const int k0    = kb * 320 + kh * 160;

    const float*    ap  = wc1   + (size_t)jrow * KFEAT + k0 + half * 8;
    const _Float16* b0p = featH + (size_t)nlane * KFEAT + k0 + half * 8;
    const _Float16* b1p = featH + (size_t)(nlane + 32) * KFEAT + k0 + half * 8;

    f32x16 acc0, acc1;
#pragma unroll
    for (int i = 0; i < 16; ++i) { acc0[i] = 0.0f; acc1[i] = 0.0f; }

#pragma unroll 5
    for (int s = 0; s < 10; ++s) {
        const float4 aw0 = *(const float4*)(ap + s * 16);
        const float4 aw1 = *(const float4*)(ap + s * 16 + 4);
        union { fp16x2 v2[4]; f16x8 h; } a;
        a.v2[0] = __builtin_amdgcn_cvt_pkrtz(aw0.x, aw0.y);
        a.v2[1] = __builtin_amdgcn_cvt_pkrtz(aw0.z, aw0.w);
        a.v2[2] = __builtin_amdgcn_cvt_pkrtz(aw1.x, aw1.y);
        a.v2[3] = __builtin_amdgcn_cvt_pkrtz(aw1.z, aw1.w);

        union { int4 q; f16x8 h; } b0, b1;
        b0.q = *(const int4*)(b0p + s * 16);
        b1.q = *(const int4*)(b1p + s * 16);

        acc0 = __builtin_amdgcn_mfma_f32_32x32x16_f16(a.h, b0.h, acc0, 0, 0, 0);
        acc1 = __builtin_amdgcn_mfma_f32_32x32x16_f16(a.h, b1.h, acc1, 0, 0, 0);
    }

    if (kh == 1) {
        float* rp = red + jq * 2048;
#pragma unroll
        for (int reg = 0; reg < 16; ++reg) {
            rp[(reg * 2 + half) * 64 + nlane]      = acc0[reg];
            rp[(reg * 2 + half) * 64 + 32 + nlane] = acc1[reg];
        }
    }
    __syncthreads();
    if (kh == 0) {
        const float* rp = red + jq * 2048;
        float* pt = part + (size_t)kb * 8192;
#pragma unroll
        for (int reg = 0; reg < 16; ++reg) {
            int j = jq * 32 + (reg & 3) + 8 * (reg >> 2) + 4 * half;
            float v0 = acc0[reg] + rp[(reg * 2 + half) * 64 + nlane];
            float v1 = acc1[reg] + rp[(reg * 2 + half) * 64 + 32 + nlane];
            pt[j * 64 + nlane]      = v0;   // coalesced, disjoint
            pt[j * 64 + 32 + nlane] = v1;
        }
    }
}

// ---------------------------------------------------------------------------
// Reduce (R10): h[e] = sum_kb part[kb][e]. 32 blocks x 256 = 8192 threads,
// coalesced within each kb plane; 4 independent accumulators + unroll keep
// ~16 loads in flight (R2's version had a serial 173-load chain at 32
// blocks = under-parallelized). part is L2-resident (5.7MB just written).
// ---------------------------------------------------------------------------
__global__ __launch_bounds__(256) void reduce_kernel(
    const float* __restrict__ part, float* __restrict__ h_ws)
{
    const int e = blockIdx.x * 256 + threadIdx.x;   // 0..8191
    const float* p = part + e;
    float s0 = 0.0f, s1 = 0.0f, s2 = 0.0f, s3 = 0.0f;
#pragma unroll 4
    for (int kb = 0; kb < 172; kb += 4) {
        s0 += p[(size_t)(kb + 0) * 8192];
        s1 += p[(size_t)(kb + 1) * 8192];
        s2 += p[(size_t)(kb + 2) * 8192];
        s3 += p[(size_t)(kb + 3) * 8192];
    }
    s0 += p[(size_t)172 * 8192];
    h_ws[e] = (s0 + s1) + (s2 + s3);
}

// ---------------------------------------------------------------------------
// FC2: one block, 512 threads. b = t&63 (coalesced h reads), j chunked 8-way.
// ---------------------------------------------------------------------------
__global__ __launch_bounds__(512) void fc2_kernel(
    const float* __restrict__ h_ws, const float* __restrict__ bc1,
    const float* __restrict__ wc2, const float* __restrict__ bc2,
    float* __restrict__ out)
{
    __shared__ float partial[512];
    const int t  = threadIdx.x;
    const int b  = t & 63;
    const int jc = t >> 6;
    float s = 0.0f;
#pragma unroll
    for (int jj = 0; jj < 16; ++jj) {
        const int j = jc * 16 + jj;
        float hv = h_ws[j * 64 + b] + bc1[j];
        hv = hv > 0.0f ? hv : 0.0f;
        s += wc2[j] * hv;
    }
    partial[t] = s;
    __syncthreads();
    if (t < 64) {
        float r = partial[t];
#pragma unroll
        for (int k = 1; k < 8; ++k) r += partial[t + 64 * k];
        out[b] = r + bc2[0];
    }
}

extern "C" void kernel_launch(void* const* d_in, const int* in_sizes, int n_in,
                              void* d_out, int out_size, void* d_ws, size_t ws_size,
                              hipStream_t stream)
{
    const float* x     = (const float*)d_in[0];
    const float* w1    = (const float*)d_in[1];
    const float* b1    = (const float*)d_in[2];
    const float* g1    = (const float*)d_in[3];
    const float* beta1 = (const float*)d_in[4];
    const float* m1    = (const float*)d_in[5];
    const float* v1    = (const float*)d_in[6];
    const float* w2    = (const float*)d_in[7];
    const float* b2    = (const float*)d_in[8];
    const float* g2    = (const float*)d_in[9];
    const float* beta2 = (const float*)d_in[10];
    const float* m2    = (const float*)d_in[11];
    const float* v2    = (const float*)d_in[12];
    const float* wc1   = (const float*)d_in[13];
    const float* bc1   = (const float*)d_in[14];
    const float* wc2   = (const float*)d_in[15];
    const float* bc2   = (const float*)d_in[16];

    char* ws = (char*)d_ws;
    _Float16* featH = (_Float16*)ws;                          // 7,086,080 B
    float*    part  = (float*)(ws + 7086080);                 // 5,668,864 B
    _Float16* w2T_g = (_Float16*)(ws + 12754944);             // 1,240,064 B
    _Float16* w1T_g = (_Float16*)(ws + 13995008);             // 177,152 B
    float*    sc_g  = (float*)(ws + 14172160);                // 66,432 B
    float*    h_ws  = (float*)(ws + 14238592);                // 32,768 B

    hipLaunchKernelGGL(prep_kernel, dim3(2834), dim3(256), 0, stream,
                       w1, b1, g1, beta1, m1, v1,
                       w2, b2, g2, beta2, m2, v2, w2T_g, w1T_g, sc_g);

    hipLaunchKernelGGL(tower_kernel, dim3(C_CH, 16), dim3(320), 0, stream,
                       x, w2T_g, w1T_g, sc_g, featH);

    hipLaunchKernelGGL(fc1_kernel, dim3(C_CH), dim3(512), 0, stream,
                       featH, wc1, part);

    hipLaunchKernelGGL(reduce_kernel, dim3(32), dim3(256), 0, stream,
                       part, h_ws);

    hipLaunchKernelGGL(fc2_kernel, dim3(1), dim3(512), 0, stream,
                       h_ws, bc1, wc2, bc2, (float*)d_out);
}

// Round 11
// 183.385 us; speedup vs baseline: 1.0889x; 1.0730x over previous
//
#include <hip/hip_runtime.h>

#define C_CH 173
#define L_IN 400
#define EPSV 1e-5f
#define KFEAT 55360  // C*32*10

typedef __fp16   fp16x2 __attribute__((ext_vector_type(2)));
typedef _Float16 f16x8  __attribute__((ext_vector_type(8)));
typedef float    f32x4  __attribute__((ext_vector_type(4)));
typedef float    f32x16 __attribute__((ext_vector_type(16)));

// y1T row: 16 f16 + 1 pad dword = 9 dwords (R2/R3/R7-proven, conflict-free).
#define Y1T_STRIDE_I 9
#define Y1T_ROWS   406  // row r = y1 time t+3; rows 0..2, 403..405 zeroed halo

// segmax: [f][sub], sub = 0..99. Stride 102 f16 = 51 dwords (R3-proven).
#define SEG_STRIDE 102

#define N1 (173 * 3584)  // w2T elems
#define N2 (173 * 512)   // w1T elems
#define N3 (173 * 96)    // BN consts per c

// ---------------------------------------------------------------------------
// Prep kernel (R10-exact + zeroes the reduce_fc2 semaphore).
// ---------------------------------------------------------------------------
__global__ __launch_bounds__(256) void prep_kernel(
    const float* __restrict__ w1, const float* __restrict__ b1,
    const float* __restrict__ g1, const float* __restrict__ beta1,
    const float* __restrict__ m1, const float* __restrict__ v1,
    const float* __restrict__ w2, const float* __restrict__ b2,
    const float* __restrict__ g2, const float* __restrict__ beta2,
    const float* __restrict__ m2, const float* __restrict__ v2,
    _Float16* __restrict__ w2T_g, _Float16* __restrict__ w1T_g,
    float* __restrict__ sc_g, unsigned int* __restrict__ cnt)
{
    const int idx = blockIdx.x * 256 + threadIdx.x;
    if (idx < N1) {
        int c = idx / 3584, r = idx - c * 3584;
        int dt = r >> 9, fg = r & 511;
        int f = fg >> 4, g = fg & 15;
        w2T_g[idx] = (_Float16)w2[c * 3584 + f * 112 + g * 7 + dt];
    } else if (idx < N1 + N2) {
        int j = idx - N1;
        int c = j / 512, r = j - c * 512;
        int g = r >> 5, k = r & 31;
        w1T_g[j] = (k < 9) ? (_Float16)w1[c * 144 + g * 9 + k] : (_Float16)0.0f;
    } else if (idx < N1 + N2 + N3) {
        int j = idx - N1 - N2;
        int c = j / 96, r = j - c * 96;
        float o;
        if (r < 32) {
            int g  = r & 15;
            int cf = c * 16 + g;
            float inv = g1[cf] * rsqrtf(v1[cf] + EPSV);
            o = (r < 16) ? inv : (b1[cf] - m1[cf]) * inv + beta1[cf];
        } else {
            int f  = (r - 32) & 31;
            int cf = c * 32 + f;
            float inv = g2[cf] * rsqrtf(v2[cf] + EPSV);
            o = (r < 64) ? inv : (b2[cf] - m2[cf]) * inv + beta2[cf];
        }
        sc_g[j] = o;
    } else if (idx == N1 + N2 + N3) {
        cnt[0] = 0u;
    }
}

// ---------------------------------------------------------------------------
// Tower kernel R11: R7 structure, 448 threads (7 waves, was 5).
// Motivation (R10 post-mortem): conv2's 13 tiles over 5 waves = {3,3,3,2,2}
// -> span 3 with 2 waves idle; 7 waves -> {2,2,2,2,2,2,1} span 2 (-33%);
// conv1 25 tiles: span 5 -> 4 (-20%); x-stage 432: 2 passes -> 1;
// w2 staging: exactly 1 int4/thread. LDS unchanged -> 4 blocks/CU x 7 =
// 28 waves/CU (was 25). All index maps audited: conv1 tile=wv+7i covers
// 0..24 exactly once; pool guarded tid<320; barriers wave-uniform.
// ---------------------------------------------------------------------------
__global__ __launch_bounds__(448, 7) void tower_kernel(
    const float* __restrict__ x,
    const _Float16* __restrict__ w2T_g, const _Float16* __restrict__ w1T_g,
    const float* __restrict__ sc_g,
    _Float16* __restrict__ featH)
{
    __shared__ __align__(16) _Float16 xa_s[432];             // xa[i] = x_s[i]
    __shared__ __align__(16) _Float16 xb_s[432];             // xb[i] = x_s[i+1]
    __shared__ __align__(16) _Float16 w1T_s[16 * 32];        // [g][k]
    __shared__ __align__(16) _Float16 y1T_s[Y1T_ROWS * 2 * Y1T_STRIDE_I];
    __shared__ __align__(16) _Float16 w2T_s[7 * 512];        // [dt][f][g]
    __shared__ _Float16               segmax_s[32 * SEG_STRIDE]; // [f][sub]
    __shared__ __align__(16) float    cst_s[96];  // s1[16] sh1[16] s2[32] sh2[32]

    const int c   = blockIdx.x;
    const int tid = threadIdx.x;

    // ---- once-per-block staging (coalesced, no div/cvt/scatter) ----
    {
        const int4* w2src = (const int4*)(w2T_g + (size_t)c * 3584);
        ((int4*)w2T_s)[tid] = w2src[tid];            // 448 int4 = 448 threads
        const int4* w1src = (const int4*)(w1T_g + c * 512);
        if (tid < 64) ((int4*)w1T_s)[tid] = w1src[tid];
        const float4* csrc = (const float4*)(sc_g + c * 96);
        if (tid >= 64 && tid < 88) ((float4*)cst_s)[tid - 64] = csrc[tid - 64];
        // zero y1T halo rows 0..2 and 403..405 (6 rows x 9 dwords)
        if (tid >= 88 && tid < 142) {
            int i = tid - 88;
            int r = i / 9, cx = i - r * 9;
            int row = (r < 3) ? r : (400 + r);
            ((int*)y1T_s)[row * Y1T_STRIDE_I + cx] = 0;
        }
    }
    __syncthreads();
    // per-lane BN consts for conv2/pool (f = tid&31 in both scopes)
    const float s2f  = cst_s[32 + (tid & 31)];
    const float sh2f = cst_s[64 + (tid & 31)];

    // ---- hoisted conv2 weight fragments (loop-invariant across batches) ----
    const int nlaneH = tid & 31;
    const int halfH  = (tid >> 5) & 1;
    union F8q { int4 q; f16x8 h; } af[7];
#pragma unroll
    for (int dt = 0; dt < 7; ++dt)
        af[dt].q = *(const int4*)((const int*)w2T_s + dt * 256 + nlaneH * 8 + halfH * 4);

    for (int nb = 0; nb < 4; ++nb) {
        const int b = blockIdx.y * 4 + nb;

        // ---- stage x as f16 parity copies (single pass at 448 threads) ----
        const float* xrow = x + ((size_t)b * C_CH + c) * L_IN;
        if (tid < 432) {
            float v = (tid >= 4 && tid < 404) ? xrow[tid - 4] : 0.0f;
            _Float16 h = (_Float16)v;
            xa_s[tid] = h;
            if (tid > 0) xb_s[tid - 1] = h;
        }
        if (tid == 0) xb_s[431] = (_Float16)0.0f;
        __syncthreads();

        // ---- conv1 via mfma_16x16x32_f16 -> y1T (25 tiles over 7 waves) ----
        // A[m=g][k]=w1T; B[k][n]=x_s[t0+n+k-4] (+4 shift folded into x_s).
        {
            const int lane = tid & 63;
            const int wv7  = tid >> 6;
            const int nl   = lane & 15;
            const int q    = lane >> 4;
            union { int4 v; f16x8 h; } a1;
            a1.v = *(const int4*)((const int*)w1T_s + nl * 16 + q * 4);
            float s1r[4], sh1r[4];
#pragma unroll
            for (int r = 0; r < 4; ++r) {
                s1r[r]  = cst_s[q * 4 + r];
                sh1r[r] = cst_s[16 + q * 4 + r];
            }
            const int* xsel = (const int*)((nl & 1) ? xb_s : xa_s);
            for (int tile = wv7; tile < 25; tile += 7) {
                const int t0 = tile * 16;
                const int dw = (t0 + nl + q * 8) >> 1;
                union { int4 v; f16x8 h; } bf;
                bf.v.x = xsel[dw];
                bf.v.y = xsel[dw + 1];
                bf.v.z = xsel[dw + 2];
                bf.v.w = xsel[dw + 3];
                f32x4 acc = {0.0f, 0.0f, 0.0f, 0.0f};
                acc = __builtin_amdgcn_mfma_f32_16x16x32_f16(a1.h, bf.h, acc, 0, 0, 0);
                union { _Float16 h[4]; int2 d; } pk;
#pragma unroll
                for (int r = 0; r < 4; ++r) {
                    float v = acc[r] * s1r[r] + sh1r[r];
                    pk.h[r] = (_Float16)(v > 0.0f ? v : 0.0f);
                }
                // stride-9 rows are only 4B aligned: two b32 stores
                int* yp = (int*)y1T_s + (t0 + nl + 3) * Y1T_STRIDE_I + q * 2;
                yp[0] = pk.d.x;
                yp[1] = pk.d.y;
            }
        }
        __syncthreads();

        // ---- conv2 MFMA (swapped operands) + scaled per-lane subseg max ----
        // acc = D[t][f]: f = lane&31, t = t0 + (reg&3) + 8*(reg>>2) + 4*half.
        // 13 tiles over 7 waves (span 2, was 3).
        {
            const int wv7   = tid >> 6;
            const int nlane = nlaneH;
            const int half  = halfH;

            for (int tile = wv7; tile < 13; tile += 7) {
                const int tA  = tile * 32 + nlane;
                const int tAr = tA < 400 ? tA : 399;   // clamp; bad rows discarded
                f32x16 acc;
#pragma unroll
                for (int i = 0; i < 16; ++i) acc[i] = 0.0f;

#pragma unroll
                for (int dt = 0; dt < 7; ++dt) {
                    const int* p = (const int*)y1T_s + (tAr + dt) * Y1T_STRIDE_I + half * 4;
                    union { int d[4]; f16x8 h; } bf;
                    bf.d[0] = p[0];
                    bf.d[1] = p[1];
                    bf.d[2] = p[2];
                    bf.d[3] = p[3];
                    acc = __builtin_amdgcn_mfma_f32_32x32x16_f16(bf.h, af[dt].h, acc, 0, 0, 0);
                }

                const int base = nlane * SEG_STRIDE + tile * 8 + half;
#pragma unroll
                for (int q = 0; q < 4; ++q) {
                    // scale per element (sign-safe wrt g2), defer shift+relu
                    float v0 = acc[4 * q + 0] * s2f;
                    float v1 = acc[4 * q + 1] * s2f;
                    float v2 = acc[4 * q + 2] * s2f;
                    float v3 = acc[4 * q + 3] * s2f;
                    float m  = fmaxf(fmaxf(v0, v1), fmaxf(v2, v3));
                    const int sub = tile * 8 + 2 * q + half;
                    if (sub < 100) segmax_s[base + 2 * q] = (_Float16)m;
                }
            }
        }
        __syncthreads();

        // ---- pool(40) = max of 10 subseg-maxes; apply shift + relu ----
        if (tid < 320) {
            const int f = tid & 31;
            const int p = tid >> 5;
            float m = -3.0e38f;
#pragma unroll
            for (int k = 0; k < 10; ++k)
                m = fmaxf(m, (float)segmax_s[f * SEG_STRIDE + p * 10 + k]);
            float v = fmaxf(m + sh2f, 0.0f);
            featH[(size_t)b * KFEAT + (c * 32 + f) * 10 + p] = (_Float16)v;
        }
        // no trailing sync needed (R2-proven argument, wave-count-agnostic):
        // next x-stage writes xa/xb whose readers are fenced by two syncs;
        // segmax(i) reads finish before the next post-x-stage sync; y1T is
        // rewritten only after the post-x-stage + post-conv1 syncs.
    }
}

// ---------------------------------------------------------------------------
// FC1: R10-exact (passed). 173 blocks x 512 threads; kh split via LDS;
// coalesced disjoint stores to part[kb][8192].
// ---------------------------------------------------------------------------
__global__ __launch_bounds__(512) void fc1_kernel(
    const _Float16* __restrict__ featH, const float* __restrict__ wc1,
    float* __restrict__ part)
{
    __shared__ float red[4 * 2048];

    const int tid   = threadIdx.x;
    const int kb    = blockIdx.x;
    const int w     = tid >> 6;
    const int lane  = tid & 63;
    const int nlane = lane & 31;
    const int half  = lane >> 5;
    const int kh    = w >> 2;
    const int jq    = w & 3;
    const int jrow  = jq * 32 + nlane;
    const int k0    = kb * 320 + kh * 160;

    const float*    ap  = wc1   + (size_t)jrow * KFEAT + k0 + half * 8;
    const _Float16* b0p = featH + (size_t)nlane * KFEAT + k0 + half * 8;
    const _Float16* b1p = featH + (size_t)(nlane + 32) * KFEAT + k0 + half * 8;

    f32x16 acc0, acc1;
#pragma unroll
    for (int i = 0; i < 16; ++i) { acc0[i] = 0.0f; acc1[i] = 0.0f; }

#pragma unroll 5
    for (int s = 0; s < 10; ++s) {
        const float4 aw0 = *(const float4*)(ap + s * 16);
        const float4 aw1 = *(const float4*)(ap + s * 16 + 4);
        union { fp16x2 v2[4]; f16x8 h; } a;
        a.v2[0] = __builtin_amdgcn_cvt_pkrtz(aw0.x, aw0.y);
        a.v2[1] = __builtin_amdgcn_cvt_pkrtz(aw0.z, aw0.w);
        a.v2[2] = __builtin_amdgcn_cvt_pkrtz(aw1.x, aw1.y);
        a.v2[3] = __builtin_amdgcn_cvt_pkrtz(aw1.z, aw1.w);

        union { int4 q; f16x8 h; } b0, b1;
        b0.q = *(const int4*)(b0p + s * 16);
        b1.q = *(const int4*)(b1p + s * 16);

        acc0 = __builtin_amdgcn_mfma_f32_32x32x16_f16(a.h, b0.h, acc0, 0, 0, 0);
        acc1 = __builtin_amdgcn_mfma_f32_32x32x16_f16(a.h, b1.h, acc1, 0, 0, 0);
    }

    if (kh == 1) {
        float* rp = red + jq * 2048;
#pragma unroll
        for (int reg = 0; reg < 16; ++reg) {
            rp[(reg * 2 + half) * 64 + nlane]      = acc0[reg];
            rp[(reg * 2 + half) * 64 + 32 + nlane] = acc1[reg];
        }
    }
    __syncthreads();
    if (kh == 0) {
        const float* rp = red + jq * 2048;
        float* pt = part + (size_t)kb * 8192;
#pragma unroll
        for (int reg = 0; reg < 16; ++reg) {
            int j = jq * 32 + (reg & 3) + 8 * (reg >> 2) + 4 * half;
            float v0 = acc0[reg] + rp[(reg * 2 + half) * 64 + nlane];
            float v1 = acc1[reg] + rp[(reg * 2 + half) * 64 + 32 + nlane];
            pt[j * 64 + nlane]      = v0;   // coalesced, disjoint
            pt[j * 64 + 32 + nlane] = v1;
        }
    }
}

// ---------------------------------------------------------------------------
// Merged reduce + FC2 (R11): 64 blocks x 256. Each block reduces a disjoint
// 128-element slice of h over 173 kb planes (coalesced 512B rows, two
// t-halves split the kb range, 4 accumulators for ILP). Split-K semaphore
// (R9-proven pattern): last arriver re-reads h with agent-scope loads and
// computes out[64]. Saves one launch gap + standalone fc2 latency.
// ---------------------------------------------------------------------------
__global__ __launch_bounds__(256) void reduce_fc2_kernel(
    const float* __restrict__ part, const float* __restrict__ bc1,
    const float* __restrict__ wc2, const float* __restrict__ bc2,
    float* __restrict__ h_ws, unsigned int* __restrict__ cnt,
    float* __restrict__ out)
{
    __shared__ float buf[256];
    __shared__ unsigned int isLast;

    const int m = blockIdx.x;          // 0..63
    const int t = threadIdx.x;
    const int e = m * 128 + (t & 127); // element slice
    const int kk = t >> 7;             // kb-range half
    const int n  = kk ? 85 : 88;       // 88 + 85 = 173
    const float* p = part + (size_t)(kk ? 88 : 0) * 8192 + e;

    float s0 = 0.0f, s1 = 0.0f, s2 = 0.0f, s3 = 0.0f;
    int kb = 0;
    for (; kb + 4 <= n; kb += 4) {
        s0 += p[(size_t)(kb + 0) * 8192];
        s1 += p[(size_t)(kb + 1) * 8192];
        s2 += p[(size_t)(kb + 2) * 8192];
        s3 += p[(size_t)(kb + 3) * 8192];
    }
    for (; kb < n; ++kb) s0 += p[(size_t)kb * 8192];
    buf[t] = (s0 + s1) + (s2 + s3);
    __syncthreads();
    if (t < 128) h_ws[e] = buf[t] + buf[t + 128];

    // ---- semaphore: last block to finish computes FC2 ----
    __syncthreads();
    if (t == 0) {
        __threadfence();
        unsigned int old = __hip_atomic_fetch_add(
            cnt, 1u, __ATOMIC_ACQ_REL, __HIP_MEMORY_SCOPE_AGENT);
        isLast = (old == 63u) ? 1u : 0u;
    }
    __syncthreads();
    if (isLast) {
        __threadfence();
        const int b  = t & 63;
        const int jc = t >> 6;         // 4 chunks of 32 j
        float s = 0.0f;
#pragma unroll
        for (int jj = 0; jj < 32; ++jj) {
            const int j = jc * 32 + jj;
            float hv = __hip_atomic_load(&h_ws[j * 64 + b],
                                         __ATOMIC_RELAXED,
                                         __HIP_MEMORY_SCOPE_AGENT) + bc1[j];
            hv = hv > 0.0f ? hv : 0.0f;
            s += wc2[j] * hv;
        }
        buf[t] = s;
        __syncthreads();
        if (t < 64)
            out[t] = buf[t] + buf[t + 64] + buf[t + 128] + buf[t + 192] + bc2[0];
    }
}

extern "C" void kernel_launch(void* const* d_in, const int* in_sizes, int n_in,
                              void* d_out, int out_size, void* d_ws, size_t ws_size,
                              hipStream_t stream)
{
    const float* x     = (const float*)d_in[0];
    const float* w1    = (const float*)d_in[1];
    const float* b1    = (const float*)d_in[2];
    const float* g1    = (const float*)d_in[3];
    const float* beta1 = (const float*)d_in[4];
    const float* m1    = (const float*)d_in[5];
    const float* v1    = (const float*)d_in[6];
    const float* w2    = (const float*)d_in[7];
    const float* b2    = (const float*)d_in[8];
    const float* g2    = (const float*)d_in[9];
    const float* beta2 = (const float*)d_in[10];
    const float* m2    = (const float*)d_in[11];
    const float* v2    = (const float*)d_in[12];
    const float* wc1   = (const float*)d_in[13];
    const float* bc1   = (const float*)d_in[14];
    const float* wc2   = (const float*)d_in[15];
    const float* bc2   = (const float*)d_in[16];

    char* ws = (char*)d_ws;
    _Float16*     featH = (_Float16*)ws;                      // 7,086,080 B
    float*        part  = (float*)(ws + 7086080);             // 5,668,864 B
    _Float16*     w2T_g = (_Float16*)(ws + 12754944);         // 1,240,064 B
    _Float16*     w1T_g = (_Float16*)(ws + 13995008);         // 177,152 B
    float*        sc_g  = (float*)(ws + 14172160);            // 66,432 B
    float*        h_ws  = (float*)(ws + 14238592);            // 32,768 B
    unsigned int* cnt   = (unsigned int*)(ws + 14271360);     // 4 B

    hipLaunchKernelGGL(prep_kernel, dim3(2834), dim3(256), 0, stream,
                       w1, b1, g1, beta1, m1, v1,
                       w2, b2, g2, beta2, m2, v2, w2T_g, w1T_g, sc_g, cnt);

    hipLaunchKernelGGL(tower_kernel, dim3(C_CH, 16), dim3(448), 0, stream,
                       x, w2T_g, w1T_g, sc_g, featH);

    hipLaunchKernelGGL(fc1_kernel, dim3(C_CH), dim3(512), 0, stream,
                       featH, wc1, part);

    hipLaunchKernelGGL(reduce_fc2_kernel, dim3(64), dim3(256), 0, stream,
                       part, bc1, wc2, bc2, h_ws, cnt, (float*)d_out);
}